// Round 16
// baseline (876.065 us; speedup 1.0000x reference)
//
#include <hip/hip_runtime.h>
#include <math.h>
#include <float.h>

#define NB 8
#define NP 2048
#define KNN 20
#define BN_EPS 1e-5f

typedef __attribute__((ext_vector_type(8))) short short8v;
typedef __attribute__((ext_vector_type(4))) float f32x4;
typedef __attribute__((ext_vector_type(16))) float f32x16;

// ---------------------------------------------------------------- helpers
__device__ __forceinline__ float leakyf(float x, float s) { return x >= 0.f ? x : s * x; }

__device__ __forceinline__ unsigned short f2bf(float f) {
  unsigned u = __float_as_uint(f);
  u = u + 0x7fffu + ((u >> 16) & 1u);
  return (unsigned short)(u >> 16);
}
__device__ __forceinline__ float bf2f(unsigned short h) {
  return __uint_as_float((unsigned)h << 16);
}
// order-preserving float->uint map (no NaNs in our data)
__device__ __forceinline__ unsigned sortkey(float f) {
  unsigned u = __float_as_uint(f);
  return (u & 0x80000000u) ? ~u : (u | 0x80000000u);
}

// dst[b][row0+c][n] = src[b][c][n]
__global__ void copy_ch_k(const float* __restrict__ src, int srcC,
                          float* __restrict__ dst, int dstC, int row0, int nch) {
  int i = blockIdx.x * 256 + threadIdx.x;
  int total = NB * nch * NP;
  if (i < total) {
    int n = i & (NP - 1); int t = i >> 11; int c = t % nch; int b = t / nch;
    dst[((size_t)b * dstC + row0 + c) * NP + n] = src[((size_t)b * srcC + c) * NP + n];
  }
}

// xx[b][n] = sum_c src[b][c][n]^2
__global__ void xx_k(const float* __restrict__ src, int C, float* __restrict__ xx) {
  int i = blockIdx.x * 256 + threadIdx.x;
  if (i < NB * NP) {
    int n = i & (NP - 1); int b = i >> 11;
    const float* xb = src + (size_t)b * C * NP + n;
    float s = 0.f;
    for (int c = 0; c < C; ++c) { float v = xb[(size_t)c * NP]; s += v * v; }
    xx[i] = s;
  }
}

// ---------------- merged weight/bn prep (single launch) ----------------
__global__ void prepall_k(const float* __restrict__ c1w, const float* __restrict__ mlpw,
                          const float* __restrict__ p1w, const float* __restrict__ c2w,
                          const float* __restrict__ p2w, const float* __restrict__ c3w,
                          const float* g2, const float* b2, const float* m2, const float* v2,
                          const float* pg, const float* pb, const float* pm, const float* pv,
                          const float* g3, const float* b3, const float* m3, const float* v3,
                          float* __restrict__ wn1t, float* __restrict__ wc1t,
                          float* __restrict__ mlp_wt, float* __restrict__ p1_wt,
                          unsigned short* __restrict__ Wnc, unsigned short* __restrict__ p2wB,
                          unsigned short* __restrict__ W3p,
                          float* __restrict__ fold2, float* __restrict__ fold3) {
  int i = blockIdx.x * 256 + threadIdx.x;
  if (i < 19 * 64) {                    // conv1 weight-combine, [c][o] layout
    int c = i >> 6, o = i & 63;
    float wd = c1w[o * 57 + 38 + c];
    wn1t[i] = c1w[o * 57 + c] - wd;
    wc1t[i] = c1w[o * 57 + 19 + c] + wd;
    return;
  }
  i -= 19 * 64;
  if (i < 19 * 256) {                   // mlp transpose (256x19 -> [c][o])
    int o = i / 19, c = i - o * 19;
    mlp_wt[c * 256 + o] = mlpw[i];
    return;
  }
  i -= 19 * 256;
  if (i < 64 * 64) {                    // p1 transpose
    int o = i >> 6, c = i & 63;
    p1_wt[c * 64 + o] = p1w[i];
    return;
  }
  i -= 64 * 64;
  if (i < 256 * 192) {                  // Wnc: [o][0:96]=nb', [o][96:192]=ctr'
    int o = i / 192, c = i - o * 192;
    unsigned short v = 0;
    if (c < 83) v = f2bf(c2w[o * 249 + c] - c2w[o * 249 + 166 + c]);
    else if (c >= 96 && c < 96 + 83) {
      int cc = c - 96;
      v = f2bf(c2w[o * 249 + 83 + cc] + c2w[o * 249 + 166 + cc]);
    }
    Wnc[i] = v;
    return;
  }
  i -= 256 * 192;
  if (i < 256 * 256) { p2wB[i] = f2bf(p2w[i]); return; }
  i -= 256 * 256;
  if (i < 512 * 512) {                  // W3p straight cast (K=512)
    W3p[i] = f2bf(c3w[i]);
    return;
  }
  i -= 512 * 512;
  if (i < 256) {
    int o = i;
    float s2 = g2[o] / sqrtf(v2[o] + BN_EPS);
    fold2[o] = s2; fold2[256 + o] = b2[o] - m2[o] * s2;
    float sp = pg[o] / sqrtf(pv[o] + BN_EPS);
    fold2[512 + o] = sp; fold2[768 + o] = pb[o] - pm[o] * sp;
    return;
  }
  i -= 256;
  if (i < 512) {
    int o = i;
    float s = g3[o] / sqrtf(v3[o] + BN_EPS);
    fold3[o] = s;
    fold3[512 + o] = b3[o] - m3[o] * s;
  }
}
#define PREPALL_TOTAL (19*64 + 19*256 + 64*64 + 256*192 + 256*256 + 512*512 + 256 + 512)

// pack pw1 (from Wnc, KS=12, stride 192) and pw2 (from p2wB, KS=16, stride 256)
__global__ void packall_k(const unsigned short* __restrict__ Wnc,
                          const unsigned short* __restrict__ p2wB,
                          unsigned short* __restrict__ pw1, unsigned short* __restrict__ pw2) {
  int i = blockIdx.x * 256 + threadIdx.x;
  if (i < 8 * 12 * 64) {
    int lane = i & 63, ks = (i >> 6) % 12, ot = i / (64 * 12);
    int o = ot * 32 + (lane & 31), c = ks * 16 + 8 * (lane >> 5);
#pragma unroll
    for (int e = 0; e < 8; ++e) pw1[i * 8 + e] = Wnc[(size_t)o * 192 + c + e];
    return;
  }
  int j = i - 8 * 12 * 64;
  if (j < 8 * 16 * 64) {
    int lane = j & 63, ks = (j >> 6) % 16, ot = j / (64 * 16);
    int o = ot * 32 + (lane & 31), c = ks * 16 + 8 * (lane >> 5);
#pragma unroll
    for (int e = 0; e < 8; ++e) pw2[j * 8 + e] = p2wB[(size_t)o * 256 + c + e];
  }
}

// D[bz][n][m] = 2*<x_n,x_m> - xx[n] - xx[m]   (64x64 tile per block, 4x4 micro; float4 store)
#define DKC 16
__global__ __launch_bounds__(256) void dist_k(const float* __restrict__ src, int C,
                                              const float* __restrict__ xx,
                                              float* __restrict__ D, int b0) {
  __shared__ float sA[DKC][64];
  __shared__ float sB[DKC][64];
  int bz = blockIdx.z; int b = b0 + bz;
  int n0 = blockIdx.x * 64, m0 = blockIdx.y * 64;
  int tid = threadIdx.x;
  int tn = tid >> 4, tm = tid & 15;
  float acc[4][4] = {};
  const float* xb = src + (size_t)b * C * NP;
  for (int k0 = 0; k0 < C; k0 += DKC) {
    for (int t = tid; t < DKC * 64; t += 256) {
      int kk = t >> 6, i = t & 63;
      int c = k0 + kk;
      float a = 0.f, bb = 0.f;
      if (c < C) { a = xb[(size_t)c * NP + n0 + i]; bb = xb[(size_t)c * NP + m0 + i]; }
      sA[kk][i] = a; sB[kk][i] = bb;
    }
    __syncthreads();
#pragma unroll
    for (int kk = 0; kk < DKC; ++kk) {
      float av[4], bv[4];
#pragma unroll
      for (int q = 0; q < 4; ++q) { av[q] = sA[kk][tn * 4 + q]; bv[q] = sB[kk][tm * 4 + q]; }
#pragma unroll
      for (int qi = 0; qi < 4; ++qi)
#pragma unroll
        for (int qj = 0; qj < 4; ++qj) acc[qi][qj] += av[qi] * bv[qj];
    }
    __syncthreads();
  }
  const float* xxb = xx + (size_t)b * NP;
#pragma unroll
  for (int qi = 0; qi < 4; ++qi) {
    int n = n0 + tn * 4 + qi; float xn = xxb[n];
    float4 dv;
    dv.x = 2.f * acc[qi][0] - xn - xxb[m0 + tm * 4 + 0];
    dv.y = 2.f * acc[qi][1] - xn - xxb[m0 + tm * 4 + 1];
    dv.z = 2.f * acc[qi][2] - xn - xxb[m0 + tm * 4 + 2];
    dv.w = 2.f * acc[qi][3] - xn - xxb[m0 + tm * 4 + 3];
    *reinterpret_cast<float4*>(&D[((size_t)bz * NP + n) * NP + m0 + tm * 4]) = dv;
  }
}

// top-20 per row; float4 loads (v[j8*4+e] <-> m = j8*256 + lane*4 + e); packed-key butterfly
__global__ __launch_bounds__(64) void topk_k(const float* __restrict__ D,
                                             int* __restrict__ idxo, int rowbase) {
  int row = blockIdx.x;
  const float4* d4 = reinterpret_cast<const float4*>(D + (size_t)row * NP);
  int lane = threadIdx.x;
  float v[32];
#pragma unroll
  for (int j8 = 0; j8 < 8; ++j8) {
    float4 q = d4[j8 * 64 + lane];
    v[j8 * 4 + 0] = q.x; v[j8 * 4 + 1] = q.y; v[j8 * 4 + 2] = q.z; v[j8 * 4 + 3] = q.w;
  }
  int* out = idxo + (size_t)(rowbase + row) * KNN;
  for (int it = 0; it < KNN; ++it) {
    // ascending j visits this lane's m in increasing order; strict > keeps smallest m
    float bv = v[0]; int bj = 0;
#pragma unroll
    for (int j = 1; j < 32; ++j) { if (v[j] > bv) { bv = v[j]; bj = j; } }
    int bm = (bj >> 2) * 256 + lane * 4 + (bj & 3);
    unsigned long long key = ((unsigned long long)sortkey(bv) << 32) | (unsigned)(~bm);
#pragma unroll
    for (int off = 1; off < 64; off <<= 1) {
      unsigned long long ok = __shfl_xor(key, off);
      if (ok > key) key = ok;
    }
    int bmw = ~(unsigned)key;
    if (lane == 0) out[it] = bmw;
    if (((bmw >> 2) & 63) == lane) v[(bmw >> 8) * 4 + (bmw & 3)] = -FLT_MAX;
  }
}

// lafe: one thread per point -> x_manet channels 0..18 AND point-major xmanT row
__global__ __launch_bounds__(64) void lafe_k(const float* __restrict__ x, const int* __restrict__ idx,
                                             const float* __restrict__ W1, const float* __restrict__ b1,
                                             const float* __restrict__ W2, const float* __restrict__ b2,
                                             const float* __restrict__ W3, const float* __restrict__ b3,
                                             float* __restrict__ x_manet,
                                             float* __restrict__ xmanT) {
  int t = blockIdx.x * 64 + threadIdx.x;
  if (t >= NB * NP) return;
  int b = t >> 11, n = t & (NP - 1);
  const float* xb = x + (size_t)b * 3 * NP;
  float ctr[3];
#pragma unroll
  for (int c = 0; c < 3; ++c) ctr[c] = xb[c * NP + n];
  float self_s = b3[0];
#pragma unroll
  for (int o = 0; o < 16; ++o) {
    float nf = b1[o];
#pragma unroll
    for (int c = 0; c < 3; ++c) nf += ctr[c] * W1[o * 3 + c];
    self_s += nf * W3[o];
  }
  const int* id = idx + (size_t)t * KNN;
  float logit[KNN];
  float mx = -FLT_MAX;
  for (int k = 0; k < KNN; ++k) {
    int j = id[k];
    float xn[3];
#pragma unroll
    for (int c = 0; c < 3; ++c) xn[c] = ctr[c] - xb[c * NP + j];
    float natt = b3[0];
#pragma unroll
    for (int o = 0; o < 16; ++o) {
      float e = b2[o];
#pragma unroll
      for (int c = 0; c < 3; ++c) e += xn[c] * W2[o * 3 + c];
      natt += e * W3[o];
    }
    float lg = self_s + natt;
    lg = leakyf(lg, 0.01f);
    logit[k] = lg; mx = fmaxf(mx, lg);
  }
  float s = 0.f;
#pragma unroll
  for (int k = 0; k < KNN; ++k) { logit[k] = expf(logit[k] - mx); s += logit[k]; }
  float invs = 1.f / s;
  float vals[16] = {};
  for (int k = 0; k < KNN; ++k) {
    int j = id[k];
    float xn[3];
#pragma unroll
    for (int c = 0; c < 3; ++c) xn[c] = ctr[c] - xb[c * NP + j];
    float w = logit[k] * invs;
#pragma unroll
    for (int o = 0; o < 16; ++o) {
      float e = b2[o];
#pragma unroll
      for (int c = 0; c < 3; ++c) e += xn[c] * W2[o * 3 + c];
      vals[o] += w * e;
    }
  }
  float row[20];
#pragma unroll
  for (int c = 0; c < 3; ++c) {
    row[c] = ctr[c];
    x_manet[((size_t)b * 19 + c) * NP + n] = ctr[c];
  }
#pragma unroll
  for (int o = 0; o < 16; ++o) {
    float v = vals[o];
    v = v > 0.f ? v : expm1f(v);
    x_manet[((size_t)b * 19 + 3 + o) * NP + n] = v;
    row[3 + o] = v;
  }
  row[19] = 0.f;
  float4* dst = reinterpret_cast<float4*>(xmanT + (size_t)t * 20);
#pragma unroll
  for (int q = 0; q < 5; ++q)
    dst[q] = make_float4(row[q * 4], row[q * 4 + 1], row[q * 4 + 2], row[q * 4 + 3]);
}

// x_mlp = relu(bn(...)) -> actT cols [0,256) (bf16)
__global__ __launch_bounds__(256) void mlp_k(const float* __restrict__ xman, const float* __restrict__ wt,
                                             const float* __restrict__ bias,
                                             const float* __restrict__ g, const float* __restrict__ be,
                                             const float* __restrict__ m, const float* __restrict__ v,
                                             unsigned short* __restrict__ actT) {
  int o0 = (threadIdx.x & 31) * 8;
  int n = blockIdx.x * 8 + (threadIdx.x >> 5);
  int b = blockIdx.z;
  const float* xb = xman + (size_t)b * 19 * NP;
  float acc[8];
#pragma unroll
  for (int q = 0; q < 8; ++q) acc[q] = bias[o0 + q];
  for (int c = 0; c < 19; ++c) {
    float xv = xb[(size_t)c * NP + n];
    const float4* w4 = reinterpret_cast<const float4*>(wt + c * 256 + o0);
    float4 wa = w4[0], wb4 = w4[1];
    float wr[8] = {wa.x, wa.y, wa.z, wa.w, wb4.x, wb4.y, wb4.z, wb4.w};
#pragma unroll
    for (int q = 0; q < 8; ++q) acc[q] += xv * wr[q];
  }
  short8v hi8;
#pragma unroll
  for (int q = 0; q < 8; ++q) {
    int o = o0 + q;
    float inv = g[o] / sqrtf(v[o] + BN_EPS);
    float z = fmaxf((acc[q] - m[o]) * inv + be[o], 0.f);
    hi8[q] = (short)f2bf(z);
  }
  size_t base = ((size_t)b * NP + n) * 512;
  *reinterpret_cast<short8v*>(actT + base + o0) = hi8;
}

// hctr1T[b][n][o] = sum_c Wc1'[o][c] * x_manet[b][c][n]  (center path of conv1)
__global__ __launch_bounds__(256) void hctr1_k(const float* __restrict__ xman,
                                               const float* __restrict__ wc1t,
                                               float* __restrict__ hctr1T) {
  int o = threadIdx.x;
  int n = blockIdx.x * 4 + threadIdx.y;
  int b = blockIdx.z;
  const float* xb = xman + (size_t)b * 19 * NP + n;
  float acc = 0.f;
  for (int c = 0; c < 19; ++c) acc += wc1t[c * 64 + o] * xb[(size_t)c * NP];
  hctr1T[((size_t)b * NP + n) * 64 + o] = acc;
}

// conv1 (weight-combined: K=19 nb-GEMM + hctr1T) + bn + leaky0.2 + att_pool
__global__ __launch_bounds__(64, 1) void conv1pool_k(
    const float* __restrict__ xmanT, const int* __restrict__ idx,
    const float* __restrict__ wn1t, const float* __restrict__ hctr1T,
    const float* __restrict__ b1g, const float* __restrict__ b1b,
    const float* __restrict__ b1m, const float* __restrict__ b1v,
    const float* __restrict__ p1g, const float* __restrict__ p1b,
    const float* __restrict__ p1m, const float* __restrict__ p1v,
    const float* __restrict__ p1wt, const float* __restrict__ p1wb,
    float* __restrict__ x_c1) {
  __shared__ __align__(16) float sg[64 * 20];   // nb (19x20) then reused as hh (64x20)
  int t = blockIdx.x;
  int b = t >> 11, n = t & (NP - 1);
  int lane = threadIdx.x;
  if (lane < KNN) {
    int j = idx[(size_t)t * KNN + lane];
    const float4* src = reinterpret_cast<const float4*>(xmanT + ((size_t)b * NP + j) * 20);
    float4 q0 = src[0], q1 = src[1], q2 = src[2], q3 = src[3], q4 = src[4];
    float vr[20] = {q0.x,q0.y,q0.z,q0.w,q1.x,q1.y,q1.z,q1.w,q2.x,q2.y,q2.z,q2.w,
                    q3.x,q3.y,q3.z,q3.w,q4.x,q4.y,q4.z,q4.w};
#pragma unroll
    for (int c = 0; c < 19; ++c) sg[c * 20 + lane] = vr[c];
  }
  __syncthreads();
  float hc = hctr1T[((size_t)b * NP + n) * 64 + lane];
  float h[KNN];
#pragma unroll
  for (int k = 0; k < KNN; ++k) h[k] = hc;
  for (int c = 0; c < 19; ++c) {
    float wv = wn1t[c * 64 + lane];
    const float4* gp = reinterpret_cast<const float4*>(sg + c * 20);
    float4 A = gp[0], Bv = gp[1], Cv = gp[2], Dv = gp[3], E = gp[4];
    float gv[20] = {A.x,A.y,A.z,A.w,Bv.x,Bv.y,Bv.z,Bv.w,Cv.x,Cv.y,Cv.z,Cv.w,Dv.x,Dv.y,Dv.z,Dv.w,E.x,E.y,E.z,E.w};
#pragma unroll
    for (int k = 0; k < KNN; ++k) h[k] += wv * gv[k];
  }
  float inv1 = b1g[lane] / sqrtf(b1v[lane] + BN_EPS);
  float m1 = b1m[lane], bb1 = b1b[lane];
  float h1[KNN];
#pragma unroll
  for (int k = 0; k < KNN; ++k) {
    float z = (h[k] - m1) * inv1 + bb1;
    h1[k] = leakyf(z, 0.2f);
  }
  float pinv = p1g[lane] / sqrtf(p1v[lane] + BN_EPS);
  float pm = p1m[lane], pb = p1b[lane];
  __syncthreads();
#pragma unroll
  for (int k = 0; k < KNN; ++k) sg[lane * 20 + k] = fmaxf((h1[k] - pm) * pinv + pb, 0.f);
  __syncthreads();
  float act[KNN] = {};
  for (int c = 0; c < 64; ++c) {
    float wv = p1wt[c * 64 + lane];
    const float4* gp = reinterpret_cast<const float4*>(sg + c * 20);
    float4 A = gp[0], Bv = gp[1], Cv = gp[2], Dv = gp[3], E = gp[4];
    float gv[20] = {A.x,A.y,A.z,A.w,Bv.x,Bv.y,Bv.z,Bv.w,Cv.x,Cv.y,Cv.z,Cv.w,Dv.x,Dv.y,Dv.z,Dv.w,E.x,E.y,E.z,E.w};
#pragma unroll
    for (int k = 0; k < KNN; ++k) act[k] += wv * gv[k];
  }
  float wb = p1wb[lane];
  float mx = -FLT_MAX;
#pragma unroll
  for (int k = 0; k < KNN; ++k) { act[k] += wb; mx = fmaxf(mx, act[k]); }
  float s = 0.f, outv = 0.f;
#pragma unroll
  for (int k = 0; k < KNN; ++k) {
    float e = expf(act[k] - mx);
    s += e; outv += h1[k] * e;
  }
  x_c1[((size_t)b * 83 + 19 + lane) * NP + n] = outv / s;
}

// xc1T[(b*NP+n)*96 + c] = bf16(x_c1[b][c][n]); c in [0,83), pad 96
__global__ __launch_bounds__(256) void t2bf_k(const float* __restrict__ xc1,
                                              unsigned short* __restrict__ xc1T) {
  __shared__ unsigned short tile[256 * 96];  // 48 KB
  int b = blockIdx.y;
  int n0 = blockIdx.x * 256;
  int tid = threadIdx.x;
  const float* xb = xc1 + (size_t)b * 83 * NP;
  for (int c = 0; c < 83; ++c)
    tile[tid * 96 + c] = f2bf(xb[(size_t)c * NP + n0 + tid]);
#pragma unroll
  for (int c = 83; c < 96; ++c) tile[tid * 96 + c] = 0;
  __syncthreads();
  const float4* src = (const float4*)tile;
  float4* dst = (float4*)(xc1T + ((size_t)b * NP + n0) * 96);
  for (int i = tid; i < 3072; i += 256) dst[i] = src[i];
}

// ---------------- stage-3 fused MFMA kernel (k = M dim, 32x32x16, frag-order operands) ----------------
// nbF (12 KB) and hhF (32 KB) alias one buffer: nbF is dead after GEMM1 (extra barrier
// before epilogue overwrites it) -> LDS 45.5 -> 33.8 KB -> 4 blocks/CU.
__global__ __launch_bounds__(256, 4) void conv2mfma_k(
    const unsigned short* __restrict__ xc1T, const int* __restrict__ idx,
    const unsigned short* __restrict__ pw1, const unsigned short* __restrict__ pw2,
    const float* __restrict__ fold, unsigned short* __restrict__ actT) {
  __shared__ unsigned short shbuf[2 * 16 * 64 * 8];   // 32 KB (nbF then hhF)
  __shared__ int jid[64];
  unsigned short* nbF = shbuf;
  unsigned short* hhF = shbuf;
  int tid = threadIdx.x;
  int t0 = blockIdx.x * 2;
  int b = t0 >> 11, n0 = t0 & (NP - 1);

  if (tid < 64) {
    int p = tid >> 5, kk = tid & 31;
    int kc = kk < KNN ? kk : KNN - 1;
    jid[tid] = idx[(size_t)(t0 + p) * KNN + kc];
  }
  __syncthreads();
  for (int it = tid; it < 768; it += 256) {
    int p = it >= 384; int rem = it - p * 384;
    int kk = rem / 12, seg = rem - kk * 12;
    int j = jid[p * 32 + kk];
    short8v v = *reinterpret_cast<const short8v*>(xc1T + ((size_t)b * NP + j) * 96 + seg * 8);
    int ks = seg >> 1, hi = seg & 1;
    *reinterpret_cast<short8v*>(&nbF[(((p * 6 + ks) << 6) + hi * 32 + kk) * 8]) = v;
  }
  __syncthreads();

  int w = tid >> 6, l = tid & 63;
  int kk = l & 31, hi = l >> 5;
  int ot0 = w * 2, ot1 = w * 2 + 1;
  const short8v* pw1v = (const short8v*)pw1;
  const short8v* pw2v = (const short8v*)pw2;

  f32x16 acc[2][2];
#pragma unroll
  for (int p = 0; p < 2; ++p)
#pragma unroll
    for (int nt = 0; nt < 2; ++nt)
#pragma unroll
      for (int r = 0; r < 16; ++r) acc[p][nt][r] = 0.f;

#pragma unroll
  for (int ks = 0; ks < 6; ++ks) {
    short8v b0 = pw1v[(ot0 * 12 + ks) * 64 + l];
    short8v b1 = pw1v[(ot1 * 12 + ks) * 64 + l];
    short8v a0 = *reinterpret_cast<const short8v*>(&nbF[((ks << 6) + l) * 8]);
    short8v a1 = *reinterpret_cast<const short8v*>(&nbF[(((6 + ks) << 6) + l) * 8]);
    acc[0][0] = __builtin_amdgcn_mfma_f32_32x32x16_bf16(a0, b0, acc[0][0], 0, 0, 0);
    acc[0][1] = __builtin_amdgcn_mfma_f32_32x32x16_bf16(a0, b1, acc[0][1], 0, 0, 0);
    acc[1][0] = __builtin_amdgcn_mfma_f32_32x32x16_bf16(a1, b0, acc[1][0], 0, 0, 0);
    acc[1][1] = __builtin_amdgcn_mfma_f32_32x32x16_bf16(a1, b1, acc[1][1], 0, 0, 0);
  }
  const unsigned short* ct0 = xc1T + ((size_t)b * NP + n0) * 96 + 8 * hi;
  const unsigned short* ct1 = ct0 + 96;
#pragma unroll
  for (int ks = 0; ks < 6; ++ks) {
    short8v b0 = pw1v[(ot0 * 12 + 6 + ks) * 64 + l];
    short8v b1 = pw1v[(ot1 * 12 + 6 + ks) * 64 + l];
    short8v a0 = *reinterpret_cast<const short8v*>(ct0 + ks * 16);
    short8v a1 = *reinterpret_cast<const short8v*>(ct1 + ks * 16);
    acc[0][0] = __builtin_amdgcn_mfma_f32_32x32x16_bf16(a0, b0, acc[0][0], 0, 0, 0);
    acc[0][1] = __builtin_amdgcn_mfma_f32_32x32x16_bf16(a0, b1, acc[0][1], 0, 0, 0);
    acc[1][0] = __builtin_amdgcn_mfma_f32_32x32x16_bf16(a1, b0, acc[1][0], 0, 0, 0);
    acc[1][1] = __builtin_amdgcn_mfma_f32_32x32x16_bf16(a1, b1, acc[1][1], 0, 0, 0);
  }
  __syncthreads();   // all waves done reading nbF before hhF overwrites it

#pragma unroll
  for (int p = 0; p < 2; ++p)
#pragma unroll
    for (int nt = 0; nt < 2; ++nt) {
      int o = w * 64 + nt * 32 + kk;
      float s2 = fold[o], o2 = fold[256 + o];
      float sp = fold[512 + o], op = fold[768 + o];
      int cbase = (p * 16 + (o >> 4)) * 64 + ((o >> 3) & 1) * 32;
      int s = (o >> 3) & 3;
#pragma unroll
      for (int r = 0; r < 16; ++r) {
        int row = (r & 3) + 8 * (r >> 2) + 4 * hi;
        float z = leakyf(acc[p][nt][r] * s2 + o2, 0.2f);
        acc[p][nt][r] = z;
        float hh = fmaxf(z * sp + op, 0.f);
        hhF[((cbase + row) ^ s) * 8 + (o & 7)] = f2bf(hh);
      }
    }
  __syncthreads();

  f32x16 acc2[2][2];
#pragma unroll
  for (int p = 0; p < 2; ++p)
#pragma unroll
    for (int nt = 0; nt < 2; ++nt)
#pragma unroll
      for (int r = 0; r < 16; ++r) acc2[p][nt][r] = 0.f;
#pragma unroll
  for (int ks = 0; ks < 16; ++ks) {
    int sr = (l >> 5) | ((ks & 1) << 1);
    short8v b0 = pw2v[(ot0 * 16 + ks) * 64 + l];
    short8v b1 = pw2v[(ot1 * 16 + ks) * 64 + l];
    short8v a0 = *reinterpret_cast<const short8v*>(&hhF[((((ks << 6) + l)) ^ sr) * 8]);
    short8v a1 = *reinterpret_cast<const short8v*>(&hhF[(((((16 + ks) << 6) + l)) ^ sr) * 8]);
    acc2[0][0] = __builtin_amdgcn_mfma_f32_32x32x16_bf16(a0, b0, acc2[0][0], 0, 0, 0);
    acc2[0][1] = __builtin_amdgcn_mfma_f32_32x32x16_bf16(a0, b1, acc2[0][1], 0, 0, 0);
    acc2[1][0] = __builtin_amdgcn_mfma_f32_32x32x16_bf16(a1, b0, acc2[1][0], 0, 0, 0);
    acc2[1][1] = __builtin_amdgcn_mfma_f32_32x32x16_bf16(a1, b1, acc2[1][1], 0, 0, 0);
  }

#pragma unroll
  for (int p = 0; p < 2; ++p) {
    size_t base = ((size_t)b * NP + n0 + p) * 512;
#pragma unroll
    for (int nt = 0; nt < 2; ++nt) {
      int o = w * 64 + nt * 32 + kk;
      float mx = -FLT_MAX;
#pragma unroll
      for (int r = 0; r < 16; ++r) {
        int row = (r & 3) + 8 * (r >> 2) + 4 * hi;
        if (row < KNN) mx = fmaxf(mx, acc2[p][nt][r]);
      }
      mx = fmaxf(mx, __shfl_xor(mx, 32));
      float s = 0.f, num = 0.f;
#pragma unroll
      for (int r = 0; r < 16; ++r) {
        int row = (r & 3) + 8 * (r >> 2) + 4 * hi;
        if (row < KNN) {
          float e = __expf(acc2[p][nt][r] - mx);
          s += e; num += e * acc[p][nt][r];
        }
      }
      s += __shfl_xor(s, 32);
      num += __shfl_xor(num, 32);
      if (hi == 0) {
        float z = num / s;
        actT[base + 256 + o] = f2bf(z);
      }
    }
  }
}

// conv3: out = leaky(bn3(W3p @ actT), 0.2) via bf16 MFMA, K=512
__global__ __launch_bounds__(256) void conv3mfma_k(const unsigned short* __restrict__ actT,
                                                   const unsigned short* __restrict__ W3p,
                                                   const float* __restrict__ fold3,
                                                   float* __restrict__ out) {
  __shared__ unsigned short sA[128 * 64];
  __shared__ unsigned short sB[128 * 64];
  int b = blockIdx.z;
  int o0 = blockIdx.x * 128, n0 = blockIdx.y * 128;
  int tid = threadIdx.x;
  int wave = tid >> 6, lane = tid & 63;
  int wr = wave >> 1, wc = wave & 1;
  int lrow = lane & 15, lkb2 = (lane >> 4) * 16, lr4 = (lane >> 4) * 4;

  f32x4 acc[4][4];
#pragma unroll
  for (int mt = 0; mt < 4; ++mt)
#pragma unroll
    for (int nt = 0; nt < 4; ++nt) acc[mt][nt] = (f32x4){0.f, 0.f, 0.f, 0.f};

  for (int k0 = 0; k0 < 512; k0 += 64) {
    for (int i = tid; i < 2048; i += 256) {
      int half = i >> 10;
      int r = (i >> 3) & 127;
      int ci = i & 7;
      const unsigned short* src = half
          ? (actT + ((size_t)b * NP + n0 + r) * 512 + k0 + ci * 8)
          : (W3p + (size_t)(o0 + r) * 512 + k0 + ci * 8);
      short8v vv = *reinterpret_cast<const short8v*>(src);
      int byteoff = (r * 128 + ci * 16) ^ ((r & 7) << 4);
      *reinterpret_cast<short8v*>((char*)(half ? sB : sA) + byteoff) = vv;
    }
    __syncthreads();
#pragma unroll
    for (int ks = 0; ks < 2; ++ks) {
      short8v afr[4], bfr[4];
#pragma unroll
      for (int mt = 0; mt < 4; ++mt) {
        int r = wr * 64 + mt * 16 + lrow;
        afr[mt] = *reinterpret_cast<const short8v*>((char*)sA + ((r * 128 + ks * 64 + lkb2) ^ ((r & 7) << 4)));
      }
#pragma unroll
      for (int nt = 0; nt < 4; ++nt) {
        int r = wc * 64 + nt * 16 + lrow;
        bfr[nt] = *reinterpret_cast<const short8v*>((char*)sB + ((r * 128 + ks * 64 + lkb2) ^ ((r & 7) << 4)));
      }
#pragma unroll
      for (int mt = 0; mt < 4; ++mt)
#pragma unroll
        for (int nt = 0; nt < 4; ++nt)
          acc[mt][nt] = __builtin_amdgcn_mfma_f32_16x16x32_bf16(afr[mt], bfr[nt], acc[mt][nt], 0, 0, 0);
    }
    __syncthreads();
  }
#pragma unroll
  for (int mt = 0; mt < 4; ++mt) {
#pragma unroll
    for (int r = 0; r < 4; ++r) {
      int o = o0 + wr * 64 + mt * 16 + lr4 + r;
      float s3 = fold3[o], b3 = fold3[512 + o];
      float* op = out + ((size_t)b * 512 + o) * NP + n0 + wc * 64 + lrow;
#pragma unroll
      for (int nt = 0; nt < 4; ++nt) {
        float z = acc[mt][nt][r] * s3 + b3;
        op[nt * 16] = leakyf(z, 0.2f);
      }
    }
  }
}

// ---------------------------------------------------------------- launch
extern "C" void kernel_launch(void* const* d_in, const int* in_sizes, int n_in,
                              void* d_out, int out_size, void* d_ws, size_t ws_size,
                              hipStream_t stream) {
  const float* x     = (const float*)d_in[0];
  const float* law1  = (const float*)d_in[1];
  const float* lab1  = (const float*)d_in[2];
  const float* law2  = (const float*)d_in[3];
  const float* lab2  = (const float*)d_in[4];
  const float* law3  = (const float*)d_in[5];
  const float* lab3  = (const float*)d_in[6];
  const float* mlp_w = (const float*)d_in[7];
  const float* mlp_b = (const float*)d_in[8];
  const float* mlp_g = (const float*)d_in[9];
  const float* mlp_be= (const float*)d_in[10];
  const float* mlp_m = (const float*)d_in[11];
  const float* mlp_v = (const float*)d_in[12];
  const float* c1_w  = (const float*)d_in[13];
  const float* bn1_g = (const float*)d_in[14];
  const float* bn1_b = (const float*)d_in[15];
  const float* bn1_m = (const float*)d_in[16];
  const float* bn1_v = (const float*)d_in[17];
  const float* p1_g  = (const float*)d_in[18];
  const float* p1_b  = (const float*)d_in[19];
  const float* p1_m  = (const float*)d_in[20];
  const float* p1_v  = (const float*)d_in[21];
  const float* p1_w  = (const float*)d_in[22];
  const float* p1_wb = (const float*)d_in[23];
  const float* c2_w  = (const float*)d_in[24];
  const float* bn2_g = (const float*)d_in[25];
  const float* bn2_b = (const float*)d_in[26];
  const float* bn2_m = (const float*)d_in[27];
  const float* bn2_v = (const float*)d_in[28];
  const float* p2_g  = (const float*)d_in[29];
  const float* p2_b  = (const float*)d_in[30];
  const float* p2_m  = (const float*)d_in[31];
  const float* p2_v  = (const float*)d_in[32];
  const float* p2_w  = (const float*)d_in[33];
  const float* p2_wb = (const float*)d_in[34];
  const float* c3_w  = (const float*)d_in[35];
  const float* bn3_g = (const float*)d_in[36];
  const float* bn3_b = (const float*)d_in[37];
  const float* bn3_m = (const float*)d_in[38];
  const float* bn3_v = (const float*)d_in[39];

  char* wsb = (char*)d_ws;
  size_t off = 0;
  auto alloc = [&](size_t elems) -> float* {
    float* p = (float*)(wsb + off);
    off += elems * sizeof(float);
    off = (off + 255) & ~(size_t)255;
    return p;
  };
  float* wn1t   = alloc(19 * 64);
  float* wc1t   = alloc(19 * 64);
  float* mlp_wt = alloc(19 * 256);
  float* p1_wt  = alloc(64 * 64);
  unsigned short* Wnc = (unsigned short*)alloc(256 * 192 / 2);
  unsigned short* p2wB = (unsigned short*)alloc(256 * 256 / 2);
  unsigned short* pw1 = (unsigned short*)alloc(8 * 12 * 64 * 8 / 2);
  unsigned short* pw2 = (unsigned short*)alloc(8 * 16 * 64 * 8 / 2);
  unsigned short* W3p  = (unsigned short*)alloc((size_t)512 * 512 / 2);
  float* fold2  = alloc(1024);
  float* fold3  = alloc(1024);
  float* xxbuf  = alloc((size_t)NB * NP);
  float* x_manet= alloc((size_t)NB * 19 * NP);
  float* xmanT  = alloc((size_t)NB * NP * 20);
  float* x_c1   = alloc((size_t)NB * 83 * NP);
  float* hctr1T = alloc((size_t)NB * 64 * NP);
  unsigned short* xc1T = (unsigned short*)alloc((size_t)NB * NP * 96 / 2);
  unsigned short* actT = (unsigned short*)alloc((size_t)NB * NP * 512 / 2);
  int*   idxbuf = (int*)alloc((size_t)NB * NP * KNN);
  float* Dbuf   = (float*)(wsb + off);
  size_t fullD = (size_t)NB * NP * NP * sizeof(float);
  int nbc = (off + fullD <= ws_size) ? NB : 1;

  // merged weight/bn prep (2 launches total)
  prepall_k<<<(PREPALL_TOTAL + 255) / 256, 256, 0, stream>>>(
      c1_w, mlp_w, p1_w, c2_w, p2_w, c3_w,
      bn2_g, bn2_b, bn2_m, bn2_v, p2_g, p2_b, p2_m, p2_v,
      bn3_g, bn3_b, bn3_m, bn3_v,
      wn1t, wc1t, mlp_wt, p1_wt, Wnc, p2wB, W3p, fold2, fold3);
  packall_k<<<56, 256, 0, stream>>>(Wnc, p2wB, pw1, pw2);

  auto knn = [&](const float* src, int C) {
    xx_k<<<(NB * NP + 255) / 256, 256, 0, stream>>>(src, C, xxbuf);
    for (int b0 = 0; b0 < NB; b0 += nbc) {
      dist_k<<<dim3(NP / 64, NP / 64, nbc), 256, 0, stream>>>(src, C, xxbuf, Dbuf, b0);
      topk_k<<<nbc * NP, 64, 0, stream>>>(Dbuf, idxbuf, b0 * NP);
    }
  };

  // stage 1: knn on x (C=3), lafe -> x_manet rows 0..18 + point-major xmanT
  knn(x, 3);
  lafe_k<<<(NB * NP) / 64, 64, 0, stream>>>(x, idxbuf, law1, lab1, law2, lab2, law3, lab3,
                                            x_manet, xmanT);

  // mlp branch -> actT cols [0,256)
  mlp_k<<<dim3(NP / 8, 1, NB), 256, 0, stream>>>(x_manet, mlp_wt, mlp_b, mlp_g, mlp_be, mlp_m, mlp_v, actT);

  // stage 2: knn on x_manet (C=19); hctr1T; conv1+pool -> x_c1 rows 19..82
  knn(x_manet, 19);
  hctr1_k<<<dim3(NP / 4, 1, NB), dim3(64, 4), 0, stream>>>(x_manet, wc1t, hctr1T);
  conv1pool_k<<<NB * NP, 64, 0, stream>>>(xmanT, idxbuf, wn1t, hctr1T,
                                          bn1_g, bn1_b, bn1_m, bn1_v,
                                          p1_g, p1_b, p1_m, p1_v,
                                          p1_wt, p1_wb, x_c1);
  copy_ch_k<<<(NB * 19 * NP + 255) / 256, 256, 0, stream>>>(x_manet, 19, x_c1, 83, 0, 19);

  // stage 3: knn on x_c1 (C=83); transpose-cast; fused MFMA conv2+pool -> actT cols [256,512)
  knn(x_c1, 83);
  t2bf_k<<<dim3(NP / 256, NB), 256, 0, stream>>>(x_c1, xc1T);
  conv2mfma_k<<<NB * NP / 2, 256, 0, stream>>>(xc1T, idxbuf, pw1, pw2, fold2, actT);

  // conv3 (bf16 MFMA, K=512) -> out
  conv3mfma_k<<<dim3(512 / 128, NP / 128, NB), 256, 0, stream>>>(actT, W3p, fold3,
                                                                 (float*)d_out);
}

// Round 17
// 865.340 us; speedup vs baseline: 1.0124x; 1.0124x over previous
//
#include <hip/hip_runtime.h>
#include <math.h>
#include <float.h>

#define NB 8
#define NP 2048
#define KNN 20
#define BN_EPS 1e-5f

typedef __attribute__((ext_vector_type(8))) short short8v;
typedef __attribute__((ext_vector_type(4))) float f32x4;
typedef __attribute__((ext_vector_type(16))) float f32x16;

// ---------------------------------------------------------------- helpers
__device__ __forceinline__ float leakyf(float x, float s) { return x >= 0.f ? x : s * x; }

__device__ __forceinline__ unsigned short f2bf(float f) {
  unsigned u = __float_as_uint(f);
  u = u + 0x7fffu + ((u >> 16) & 1u);
  return (unsigned short)(u >> 16);
}
__device__ __forceinline__ float bf2f(unsigned short h) {
  return __uint_as_float((unsigned)h << 16);
}
// order-preserving float->uint map (no NaNs in our data)
__device__ __forceinline__ unsigned sortkey(float f) {
  unsigned u = __float_as_uint(f);
  return (u & 0x80000000u) ? ~u : (u | 0x80000000u);
}

// dst[b][row0+c][n] = src[b][c][n]
__global__ void copy_ch_k(const float* __restrict__ src, int srcC,
                          float* __restrict__ dst, int dstC, int row0, int nch) {
  int i = blockIdx.x * 256 + threadIdx.x;
  int total = NB * nch * NP;
  if (i < total) {
    int n = i & (NP - 1); int t = i >> 11; int c = t % nch; int b = t / nch;
    dst[((size_t)b * dstC + row0 + c) * NP + n] = src[((size_t)b * srcC + c) * NP + n];
  }
}

// xx[b][n] = sum_c src[b][c][n]^2
__global__ void xx_k(const float* __restrict__ src, int C, float* __restrict__ xx) {
  int i = blockIdx.x * 256 + threadIdx.x;
  if (i < NB * NP) {
    int n = i & (NP - 1); int b = i >> 11;
    const float* xb = src + (size_t)b * C * NP + n;
    float s = 0.f;
    for (int c = 0; c < C; ++c) { float v = xb[(size_t)c * NP]; s += v * v; }
    xx[i] = s;
  }
}

// ---------------- merged weight/bn prep (single launch) ----------------
__global__ void prepall_k(const float* __restrict__ c1w, const float* __restrict__ mlpw,
                          const float* __restrict__ p1w, const float* __restrict__ c2w,
                          const float* __restrict__ p2w, const float* __restrict__ c3w,
                          const float* g2, const float* b2, const float* m2, const float* v2,
                          const float* pg, const float* pb, const float* pm, const float* pv,
                          const float* g3, const float* b3, const float* m3, const float* v3,
                          float* __restrict__ wn1t, float* __restrict__ wc1t,
                          float* __restrict__ mlp_wt, float* __restrict__ p1_wt,
                          unsigned short* __restrict__ Wnc, unsigned short* __restrict__ p2wB,
                          unsigned short* __restrict__ W3p,
                          float* __restrict__ fold2, float* __restrict__ fold3) {
  int i = blockIdx.x * 256 + threadIdx.x;
  if (i < 19 * 64) {                    // conv1 weight-combine, [c][o] layout
    int c = i >> 6, o = i & 63;
    float wd = c1w[o * 57 + 38 + c];
    wn1t[i] = c1w[o * 57 + c] - wd;
    wc1t[i] = c1w[o * 57 + 19 + c] + wd;
    return;
  }
  i -= 19 * 64;
  if (i < 19 * 256) {                   // mlp transpose (256x19 -> [c][o])
    int o = i / 19, c = i - o * 19;
    mlp_wt[c * 256 + o] = mlpw[i];
    return;
  }
  i -= 19 * 256;
  if (i < 64 * 64) {                    // p1 transpose
    int o = i >> 6, c = i & 63;
    p1_wt[c * 64 + o] = p1w[i];
    return;
  }
  i -= 64 * 64;
  if (i < 256 * 192) {                  // Wnc: [o][0:96]=nb', [o][96:192]=ctr'
    int o = i / 192, c = i - o * 192;
    unsigned short v = 0;
    if (c < 83) v = f2bf(c2w[o * 249 + c] - c2w[o * 249 + 166 + c]);
    else if (c >= 96 && c < 96 + 83) {
      int cc = c - 96;
      v = f2bf(c2w[o * 249 + 83 + cc] + c2w[o * 249 + 166 + cc]);
    }
    Wnc[i] = v;
    return;
  }
  i -= 256 * 192;
  if (i < 256 * 256) { p2wB[i] = f2bf(p2w[i]); return; }
  i -= 256 * 256;
  if (i < 512 * 512) {                  // W3p straight cast (K=512)
    W3p[i] = f2bf(c3w[i]);
    return;
  }
  i -= 512 * 512;
  if (i < 256) {
    int o = i;
    float s2 = g2[o] / sqrtf(v2[o] + BN_EPS);
    fold2[o] = s2; fold2[256 + o] = b2[o] - m2[o] * s2;
    float sp = pg[o] / sqrtf(pv[o] + BN_EPS);
    fold2[512 + o] = sp; fold2[768 + o] = pb[o] - pm[o] * sp;
    return;
  }
  i -= 256;
  if (i < 512) {
    int o = i;
    float s = g3[o] / sqrtf(v3[o] + BN_EPS);
    fold3[o] = s;
    fold3[512 + o] = b3[o] - m3[o] * s;
  }
}
#define PREPALL_TOTAL (19*64 + 19*256 + 64*64 + 256*192 + 256*256 + 512*512 + 256 + 512)

// pack pw1 (from Wnc, KS=12, stride 192) and pw2 (from p2wB, KS=16, stride 256)
__global__ void packall_k(const unsigned short* __restrict__ Wnc,
                          const unsigned short* __restrict__ p2wB,
                          unsigned short* __restrict__ pw1, unsigned short* __restrict__ pw2) {
  int i = blockIdx.x * 256 + threadIdx.x;
  if (i < 8 * 12 * 64) {
    int lane = i & 63, ks = (i >> 6) % 12, ot = i / (64 * 12);
    int o = ot * 32 + (lane & 31), c = ks * 16 + 8 * (lane >> 5);
#pragma unroll
    for (int e = 0; e < 8; ++e) pw1[i * 8 + e] = Wnc[(size_t)o * 192 + c + e];
    return;
  }
  int j = i - 8 * 12 * 64;
  if (j < 8 * 16 * 64) {
    int lane = j & 63, ks = (j >> 6) % 16, ot = j / (64 * 16);
    int o = ot * 32 + (lane & 31), c = ks * 16 + 8 * (lane >> 5);
#pragma unroll
    for (int e = 0; e < 8; ++e) pw2[j * 8 + e] = p2wB[(size_t)o * 256 + c + e];
  }
}

// D[bz][n][m] = 2*<x_n,x_m> - xx[n] - xx[m]   (64x64 tile per block, 4x4 micro; float4 store)
#define DKC 16
__global__ __launch_bounds__(256) void dist_k(const float* __restrict__ src, int C,
                                              const float* __restrict__ xx,
                                              float* __restrict__ D, int b0) {
  __shared__ float sA[DKC][64];
  __shared__ float sB[DKC][64];
  int bz = blockIdx.z; int b = b0 + bz;
  int n0 = blockIdx.x * 64, m0 = blockIdx.y * 64;
  int tid = threadIdx.x;
  int tn = tid >> 4, tm = tid & 15;
  float acc[4][4] = {};
  const float* xb = src + (size_t)b * C * NP;
  for (int k0 = 0; k0 < C; k0 += DKC) {
    for (int t = tid; t < DKC * 64; t += 256) {
      int kk = t >> 6, i = t & 63;
      int c = k0 + kk;
      float a = 0.f, bb = 0.f;
      if (c < C) { a = xb[(size_t)c * NP + n0 + i]; bb = xb[(size_t)c * NP + m0 + i]; }
      sA[kk][i] = a; sB[kk][i] = bb;
    }
    __syncthreads();
#pragma unroll
    for (int kk = 0; kk < DKC; ++kk) {
      float av[4], bv[4];
#pragma unroll
      for (int q = 0; q < 4; ++q) { av[q] = sA[kk][tn * 4 + q]; bv[q] = sB[kk][tm * 4 + q]; }
#pragma unroll
      for (int qi = 0; qi < 4; ++qi)
#pragma unroll
        for (int qj = 0; qj < 4; ++qj) acc[qi][qj] += av[qi] * bv[qj];
    }
    __syncthreads();
  }
  const float* xxb = xx + (size_t)b * NP;
#pragma unroll
  for (int qi = 0; qi < 4; ++qi) {
    int n = n0 + tn * 4 + qi; float xn = xxb[n];
    float4 dv;
    dv.x = 2.f * acc[qi][0] - xn - xxb[m0 + tm * 4 + 0];
    dv.y = 2.f * acc[qi][1] - xn - xxb[m0 + tm * 4 + 1];
    dv.z = 2.f * acc[qi][2] - xn - xxb[m0 + tm * 4 + 2];
    dv.w = 2.f * acc[qi][3] - xn - xxb[m0 + tm * 4 + 3];
    *reinterpret_cast<float4*>(&D[((size_t)bz * NP + n) * NP + m0 + tm * 4]) = dv;
  }
}

// top-20 per row; float4 loads (v[j8*4+e] <-> m = j8*256 + lane*4 + e); packed-key butterfly
__global__ __launch_bounds__(64) void topk_k(const float* __restrict__ D,
                                             int* __restrict__ idxo, int rowbase) {
  int row = blockIdx.x;
  const float4* d4 = reinterpret_cast<const float4*>(D + (size_t)row * NP);
  int lane = threadIdx.x;
  float v[32];
#pragma unroll
  for (int j8 = 0; j8 < 8; ++j8) {
    float4 q = d4[j8 * 64 + lane];
    v[j8 * 4 + 0] = q.x; v[j8 * 4 + 1] = q.y; v[j8 * 4 + 2] = q.z; v[j8 * 4 + 3] = q.w;
  }
  int* out = idxo + (size_t)(rowbase + row) * KNN;
  for (int it = 0; it < KNN; ++it) {
    // ascending j visits this lane's m in increasing order; strict > keeps smallest m
    float bv = v[0]; int bj = 0;
#pragma unroll
    for (int j = 1; j < 32; ++j) { if (v[j] > bv) { bv = v[j]; bj = j; } }
    int bm = (bj >> 2) * 256 + lane * 4 + (bj & 3);
    unsigned long long key = ((unsigned long long)sortkey(bv) << 32) | (unsigned)(~bm);
#pragma unroll
    for (int off = 1; off < 64; off <<= 1) {
      unsigned long long ok = __shfl_xor(key, off);
      if (ok > key) key = ok;
    }
    int bmw = ~(unsigned)key;
    if (lane == 0) out[it] = bmw;
    if (((bmw >> 2) & 63) == lane) v[(bmw >> 8) * 4 + (bmw & 3)] = -FLT_MAX;
  }
}

// lafe: one thread per point -> x_manet channels 0..18 AND point-major xmanT row
__global__ __launch_bounds__(64) void lafe_k(const float* __restrict__ x, const int* __restrict__ idx,
                                             const float* __restrict__ W1, const float* __restrict__ b1,
                                             const float* __restrict__ W2, const float* __restrict__ b2,
                                             const float* __restrict__ W3, const float* __restrict__ b3,
                                             float* __restrict__ x_manet,
                                             float* __restrict__ xmanT) {
  int t = blockIdx.x * 64 + threadIdx.x;
  if (t >= NB * NP) return;
  int b = t >> 11, n = t & (NP - 1);
  const float* xb = x + (size_t)b * 3 * NP;
  float ctr[3];
#pragma unroll
  for (int c = 0; c < 3; ++c) ctr[c] = xb[c * NP + n];
  float self_s = b3[0];
#pragma unroll
  for (int o = 0; o < 16; ++o) {
    float nf = b1[o];
#pragma unroll
    for (int c = 0; c < 3; ++c) nf += ctr[c] * W1[o * 3 + c];
    self_s += nf * W3[o];
  }
  const int* id = idx + (size_t)t * KNN;
  float logit[KNN];
  float mx = -FLT_MAX;
  for (int k = 0; k < KNN; ++k) {
    int j = id[k];
    float xn[3];
#pragma unroll
    for (int c = 0; c < 3; ++c) xn[c] = ctr[c] - xb[c * NP + j];
    float natt = b3[0];
#pragma unroll
    for (int o = 0; o < 16; ++o) {
      float e = b2[o];
#pragma unroll
      for (int c = 0; c < 3; ++c) e += xn[c] * W2[o * 3 + c];
      natt += e * W3[o];
    }
    float lg = self_s + natt;
    lg = leakyf(lg, 0.01f);
    logit[k] = lg; mx = fmaxf(mx, lg);
  }
  float s = 0.f;
#pragma unroll
  for (int k = 0; k < KNN; ++k) { logit[k] = expf(logit[k] - mx); s += logit[k]; }
  float invs = 1.f / s;
  float vals[16] = {};
  for (int k = 0; k < KNN; ++k) {
    int j = id[k];
    float xn[3];
#pragma unroll
    for (int c = 0; c < 3; ++c) xn[c] = ctr[c] - xb[c * NP + j];
    float w = logit[k] * invs;
#pragma unroll
    for (int o = 0; o < 16; ++o) {
      float e = b2[o];
#pragma unroll
      for (int c = 0; c < 3; ++c) e += xn[c] * W2[o * 3 + c];
      vals[o] += w * e;
    }
  }
  float row[20];
#pragma unroll
  for (int c = 0; c < 3; ++c) {
    row[c] = ctr[c];
    x_manet[((size_t)b * 19 + c) * NP + n] = ctr[c];
  }
#pragma unroll
  for (int o = 0; o < 16; ++o) {
    float v = vals[o];
    v = v > 0.f ? v : expm1f(v);
    x_manet[((size_t)b * 19 + 3 + o) * NP + n] = v;
    row[3 + o] = v;
  }
  row[19] = 0.f;
  float4* dst = reinterpret_cast<float4*>(xmanT + (size_t)t * 20);
#pragma unroll
  for (int q = 0; q < 5; ++q)
    dst[q] = make_float4(row[q * 4], row[q * 4 + 1], row[q * 4 + 2], row[q * 4 + 3]);
}

// x_mlp = relu(bn(...)) -> actT cols [0,256) (bf16)
__global__ __launch_bounds__(256) void mlp_k(const float* __restrict__ xman, const float* __restrict__ wt,
                                             const float* __restrict__ bias,
                                             const float* __restrict__ g, const float* __restrict__ be,
                                             const float* __restrict__ m, const float* __restrict__ v,
                                             unsigned short* __restrict__ actT) {
  int o0 = (threadIdx.x & 31) * 8;
  int n = blockIdx.x * 8 + (threadIdx.x >> 5);
  int b = blockIdx.z;
  const float* xb = xman + (size_t)b * 19 * NP;
  float acc[8];
#pragma unroll
  for (int q = 0; q < 8; ++q) acc[q] = bias[o0 + q];
  for (int c = 0; c < 19; ++c) {
    float xv = xb[(size_t)c * NP + n];
    const float4* w4 = reinterpret_cast<const float4*>(wt + c * 256 + o0);
    float4 wa = w4[0], wb4 = w4[1];
    float wr[8] = {wa.x, wa.y, wa.z, wa.w, wb4.x, wb4.y, wb4.z, wb4.w};
#pragma unroll
    for (int q = 0; q < 8; ++q) acc[q] += xv * wr[q];
  }
  short8v hi8;
#pragma unroll
  for (int q = 0; q < 8; ++q) {
    int o = o0 + q;
    float inv = g[o] / sqrtf(v[o] + BN_EPS);
    float z = fmaxf((acc[q] - m[o]) * inv + be[o], 0.f);
    hi8[q] = (short)f2bf(z);
  }
  size_t base = ((size_t)b * NP + n) * 512;
  *reinterpret_cast<short8v*>(actT + base + o0) = hi8;
}

// hctr1T[b][n][o] = sum_c Wc1'[o][c] * x_manet[b][c][n]  (center path of conv1)
__global__ __launch_bounds__(256) void hctr1_k(const float* __restrict__ xman,
                                               const float* __restrict__ wc1t,
                                               float* __restrict__ hctr1T) {
  int o = threadIdx.x;
  int n = blockIdx.x * 4 + threadIdx.y;
  int b = blockIdx.z;
  const float* xb = xman + (size_t)b * 19 * NP + n;
  float acc = 0.f;
  for (int c = 0; c < 19; ++c) acc += wc1t[c * 64 + o] * xb[(size_t)c * NP];
  hctr1T[((size_t)b * NP + n) * 64 + o] = acc;
}

// conv1 (weight-combined: K=19 nb-GEMM + hctr1T) + bn + leaky0.2 + att_pool
__global__ __launch_bounds__(64, 1) void conv1pool_k(
    const float* __restrict__ xmanT, const int* __restrict__ idx,
    const float* __restrict__ wn1t, const float* __restrict__ hctr1T,
    const float* __restrict__ b1g, const float* __restrict__ b1b,
    const float* __restrict__ b1m, const float* __restrict__ b1v,
    const float* __restrict__ p1g, const float* __restrict__ p1b,
    const float* __restrict__ p1m, const float* __restrict__ p1v,
    const float* __restrict__ p1wt, const float* __restrict__ p1wb,
    float* __restrict__ x_c1) {
  __shared__ __align__(16) float sg[64 * 20];   // nb (19x20) then reused as hh (64x20)
  int t = blockIdx.x;
  int b = t >> 11, n = t & (NP - 1);
  int lane = threadIdx.x;
  if (lane < KNN) {
    int j = idx[(size_t)t * KNN + lane];
    const float4* src = reinterpret_cast<const float4*>(xmanT + ((size_t)b * NP + j) * 20);
    float4 q0 = src[0], q1 = src[1], q2 = src[2], q3 = src[3], q4 = src[4];
    float vr[20] = {q0.x,q0.y,q0.z,q0.w,q1.x,q1.y,q1.z,q1.w,q2.x,q2.y,q2.z,q2.w,
                    q3.x,q3.y,q3.z,q3.w,q4.x,q4.y,q4.z,q4.w};
#pragma unroll
    for (int c = 0; c < 19; ++c) sg[c * 20 + lane] = vr[c];
  }
  __syncthreads();
  float hc = hctr1T[((size_t)b * NP + n) * 64 + lane];
  float h[KNN];
#pragma unroll
  for (int k = 0; k < KNN; ++k) h[k] = hc;
  for (int c = 0; c < 19; ++c) {
    float wv = wn1t[c * 64 + lane];
    const float4* gp = reinterpret_cast<const float4*>(sg + c * 20);
    float4 A = gp[0], Bv = gp[1], Cv = gp[2], Dv = gp[3], E = gp[4];
    float gv[20] = {A.x,A.y,A.z,A.w,Bv.x,Bv.y,Bv.z,Bv.w,Cv.x,Cv.y,Cv.z,Cv.w,Dv.x,Dv.y,Dv.z,Dv.w,E.x,E.y,E.z,E.w};
#pragma unroll
    for (int k = 0; k < KNN; ++k) h[k] += wv * gv[k];
  }
  float inv1 = b1g[lane] / sqrtf(b1v[lane] + BN_EPS);
  float m1 = b1m[lane], bb1 = b1b[lane];
  float h1[KNN];
#pragma unroll
  for (int k = 0; k < KNN; ++k) {
    float z = (h[k] - m1) * inv1 + bb1;
    h1[k] = leakyf(z, 0.2f);
  }
  float pinv = p1g[lane] / sqrtf(p1v[lane] + BN_EPS);
  float pm = p1m[lane], pb = p1b[lane];
  __syncthreads();
#pragma unroll
  for (int k = 0; k < KNN; ++k) sg[lane * 20 + k] = fmaxf((h1[k] - pm) * pinv + pb, 0.f);
  __syncthreads();
  float act[KNN] = {};
  for (int c = 0; c < 64; ++c) {
    float wv = p1wt[c * 64 + lane];
    const float4* gp = reinterpret_cast<const float4*>(sg + c * 20);
    float4 A = gp[0], Bv = gp[1], Cv = gp[2], Dv = gp[3], E = gp[4];
    float gv[20] = {A.x,A.y,A.z,A.w,Bv.x,Bv.y,Bv.z,Bv.w,Cv.x,Cv.y,Cv.z,Cv.w,Dv.x,Dv.y,Dv.z,Dv.w,E.x,E.y,E.z,E.w};
#pragma unroll
    for (int k = 0; k < KNN; ++k) act[k] += wv * gv[k];
  }
  float wb = p1wb[lane];
  float mx = -FLT_MAX;
#pragma unroll
  for (int k = 0; k < KNN; ++k) { act[k] += wb; mx = fmaxf(mx, act[k]); }
  float s = 0.f, outv = 0.f;
#pragma unroll
  for (int k = 0; k < KNN; ++k) {
    float e = expf(act[k] - mx);
    s += e; outv += h1[k] * e;
  }
  x_c1[((size_t)b * 83 + 19 + lane) * NP + n] = outv / s;
}

// xc1T[(b*NP+n)*96 + c] = bf16(x_c1[b][c][n]); c in [0,83), pad 96
__global__ __launch_bounds__(256) void t2bf_k(const float* __restrict__ xc1,
                                              unsigned short* __restrict__ xc1T) {
  __shared__ unsigned short tile[256 * 96];  // 48 KB
  int b = blockIdx.y;
  int n0 = blockIdx.x * 256;
  int tid = threadIdx.x;
  const float* xb = xc1 + (size_t)b * 83 * NP;
  for (int c = 0; c < 83; ++c)
    tile[tid * 96 + c] = f2bf(xb[(size_t)c * NP + n0 + tid]);
#pragma unroll
  for (int c = 83; c < 96; ++c) tile[tid * 96 + c] = 0;
  __syncthreads();
  const float4* src = (const float4*)tile;
  float4* dst = (float4*)(xc1T + ((size_t)b * NP + n0) * 96);
  for (int i = tid; i < 3072; i += 256) dst[i] = src[i];
}

// ---------------- stage-3 fused MFMA kernel (k = M dim, 32x32x16, frag-order operands) ----------------
// nbF/hhF alias one 32 KB buffer (extra barrier between GEMM1 and epilogue);
// launch_bounds(256,3) keeps VGPR at ~84 (no spill); HW still fits 4 blocks/CU by LDS.
__global__ __launch_bounds__(256, 3) void conv2mfma_k(
    const unsigned short* __restrict__ xc1T, const int* __restrict__ idx,
    const unsigned short* __restrict__ pw1, const unsigned short* __restrict__ pw2,
    const float* __restrict__ fold, unsigned short* __restrict__ actT) {
  __shared__ unsigned short shbuf[2 * 16 * 64 * 8];   // 32 KB (nbF then hhF)
  __shared__ int jid[64];
  unsigned short* nbF = shbuf;
  unsigned short* hhF = shbuf;
  int tid = threadIdx.x;
  int t0 = blockIdx.x * 2;
  int b = t0 >> 11, n0 = t0 & (NP - 1);

  if (tid < 64) {
    int p = tid >> 5, kk = tid & 31;
    int kc = kk < KNN ? kk : KNN - 1;
    jid[tid] = idx[(size_t)(t0 + p) * KNN + kc];
  }
  __syncthreads();
  for (int it = tid; it < 768; it += 256) {
    int p = it >= 384; int rem = it - p * 384;
    int kk = rem / 12, seg = rem - kk * 12;
    int j = jid[p * 32 + kk];
    short8v v = *reinterpret_cast<const short8v*>(xc1T + ((size_t)b * NP + j) * 96 + seg * 8);
    int ks = seg >> 1, hi = seg & 1;
    *reinterpret_cast<short8v*>(&nbF[(((p * 6 + ks) << 6) + hi * 32 + kk) * 8]) = v;
  }
  __syncthreads();

  int w = tid >> 6, l = tid & 63;
  int kk = l & 31, hi = l >> 5;
  int ot0 = w * 2, ot1 = w * 2 + 1;
  const short8v* pw1v = (const short8v*)pw1;
  const short8v* pw2v = (const short8v*)pw2;

  f32x16 acc[2][2];
#pragma unroll
  for (int p = 0; p < 2; ++p)
#pragma unroll
    for (int nt = 0; nt < 2; ++nt)
#pragma unroll
      for (int r = 0; r < 16; ++r) acc[p][nt][r] = 0.f;

#pragma unroll
  for (int ks = 0; ks < 6; ++ks) {
    short8v b0 = pw1v[(ot0 * 12 + ks) * 64 + l];
    short8v b1 = pw1v[(ot1 * 12 + ks) * 64 + l];
    short8v a0 = *reinterpret_cast<const short8v*>(&nbF[((ks << 6) + l) * 8]);
    short8v a1 = *reinterpret_cast<const short8v*>(&nbF[(((6 + ks) << 6) + l) * 8]);
    acc[0][0] = __builtin_amdgcn_mfma_f32_32x32x16_bf16(a0, b0, acc[0][0], 0, 0, 0);
    acc[0][1] = __builtin_amdgcn_mfma_f32_32x32x16_bf16(a0, b1, acc[0][1], 0, 0, 0);
    acc[1][0] = __builtin_amdgcn_mfma_f32_32x32x16_bf16(a1, b0, acc[1][0], 0, 0, 0);
    acc[1][1] = __builtin_amdgcn_mfma_f32_32x32x16_bf16(a1, b1, acc[1][1], 0, 0, 0);
  }
  const unsigned short* ct0 = xc1T + ((size_t)b * NP + n0) * 96 + 8 * hi;
  const unsigned short* ct1 = ct0 + 96;
#pragma unroll
  for (int ks = 0; ks < 6; ++ks) {
    short8v b0 = pw1v[(ot0 * 12 + 6 + ks) * 64 + l];
    short8v b1 = pw1v[(ot1 * 12 + 6 + ks) * 64 + l];
    short8v a0 = *reinterpret_cast<const short8v*>(ct0 + ks * 16);
    short8v a1 = *reinterpret_cast<const short8v*>(ct1 + ks * 16);
    acc[0][0] = __builtin_amdgcn_mfma_f32_32x32x16_bf16(a0, b0, acc[0][0], 0, 0, 0);
    acc[0][1] = __builtin_amdgcn_mfma_f32_32x32x16_bf16(a0, b1, acc[0][1], 0, 0, 0);
    acc[1][0] = __builtin_amdgcn_mfma_f32_32x32x16_bf16(a1, b0, acc[1][0], 0, 0, 0);
    acc[1][1] = __builtin_amdgcn_mfma_f32_32x32x16_bf16(a1, b1, acc[1][1], 0, 0, 0);
  }
  __syncthreads();   // all waves done reading nbF before hhF overwrites it

#pragma unroll
  for (int p = 0; p < 2; ++p)
#pragma unroll
    for (int nt = 0; nt < 2; ++nt) {
      int o = w * 64 + nt * 32 + kk;
      float s2 = fold[o], o2 = fold[256 + o];
      float sp = fold[512 + o], op = fold[768 + o];
      int cbase = (p * 16 + (o >> 4)) * 64 + ((o >> 3) & 1) * 32;
      int s = (o >> 3) & 3;
#pragma unroll
      for (int r = 0; r < 16; ++r) {
        int row = (r & 3) + 8 * (r >> 2) + 4 * hi;
        float z = leakyf(acc[p][nt][r] * s2 + o2, 0.2f);
        acc[p][nt][r] = z;
        float hh = fmaxf(z * sp + op, 0.f);
        hhF[((cbase + row) ^ s) * 8 + (o & 7)] = f2bf(hh);
      }
    }
  __syncthreads();

  f32x16 acc2[2][2];
#pragma unroll
  for (int p = 0; p < 2; ++p)
#pragma unroll
    for (int nt = 0; nt < 2; ++nt)
#pragma unroll
      for (int r = 0; r < 16; ++r) acc2[p][nt][r] = 0.f;
#pragma unroll
  for (int ks = 0; ks < 16; ++ks) {
    int sr = (l >> 5) | ((ks & 1) << 1);
    short8v b0 = pw2v[(ot0 * 16 + ks) * 64 + l];
    short8v b1 = pw2v[(ot1 * 16 + ks) * 64 + l];
    short8v a0 = *reinterpret_cast<const short8v*>(&hhF[((((ks << 6) + l)) ^ sr) * 8]);
    short8v a1 = *reinterpret_cast<const short8v*>(&hhF[(((((16 + ks) << 6) + l)) ^ sr) * 8]);
    acc2[0][0] = __builtin_amdgcn_mfma_f32_32x32x16_bf16(a0, b0, acc2[0][0], 0, 0, 0);
    acc2[0][1] = __builtin_amdgcn_mfma_f32_32x32x16_bf16(a0, b1, acc2[0][1], 0, 0, 0);
    acc2[1][0] = __builtin_amdgcn_mfma_f32_32x32x16_bf16(a1, b0, acc2[1][0], 0, 0, 0);
    acc2[1][1] = __builtin_amdgcn_mfma_f32_32x32x16_bf16(a1, b1, acc2[1][1], 0, 0, 0);
  }

#pragma unroll
  for (int p = 0; p < 2; ++p) {
    size_t base = ((size_t)b * NP + n0 + p) * 512;
#pragma unroll
    for (int nt = 0; nt < 2; ++nt) {
      int o = w * 64 + nt * 32 + kk;
      float mx = -FLT_MAX;
#pragma unroll
      for (int r = 0; r < 16; ++r) {
        int row = (r & 3) + 8 * (r >> 2) + 4 * hi;
        if (row < KNN) mx = fmaxf(mx, acc2[p][nt][r]);
      }
      mx = fmaxf(mx, __shfl_xor(mx, 32));
      float s = 0.f, num = 0.f;
#pragma unroll
      for (int r = 0; r < 16; ++r) {
        int row = (r & 3) + 8 * (r >> 2) + 4 * hi;
        if (row < KNN) {
          float e = __expf(acc2[p][nt][r] - mx);
          s += e; num += e * acc[p][nt][r];
        }
      }
      s += __shfl_xor(s, 32);
      num += __shfl_xor(num, 32);
      if (hi == 0) {
        float z = num / s;
        actT[base + 256 + o] = f2bf(z);
      }
    }
  }
}

// conv3: out = leaky(bn3(W3p @ actT), 0.2) via bf16 MFMA, K=512
__global__ __launch_bounds__(256) void conv3mfma_k(const unsigned short* __restrict__ actT,
                                                   const unsigned short* __restrict__ W3p,
                                                   const float* __restrict__ fold3,
                                                   float* __restrict__ out) {
  __shared__ unsigned short sA[128 * 64];
  __shared__ unsigned short sB[128 * 64];
  int b = blockIdx.z;
  int o0 = blockIdx.x * 128, n0 = blockIdx.y * 128;
  int tid = threadIdx.x;
  int wave = tid >> 6, lane = tid & 63;
  int wr = wave >> 1, wc = wave & 1;
  int lrow = lane & 15, lkb2 = (lane >> 4) * 16, lr4 = (lane >> 4) * 4;

  f32x4 acc[4][4];
#pragma unroll
  for (int mt = 0; mt < 4; ++mt)
#pragma unroll
    for (int nt = 0; nt < 4; ++nt) acc[mt][nt] = (f32x4){0.f, 0.f, 0.f, 0.f};

  for (int k0 = 0; k0 < 512; k0 += 64) {
    for (int i = tid; i < 2048; i += 256) {
      int half = i >> 10;
      int r = (i >> 3) & 127;
      int ci = i & 7;
      const unsigned short* src = half
          ? (actT + ((size_t)b * NP + n0 + r) * 512 + k0 + ci * 8)
          : (W3p + (size_t)(o0 + r) * 512 + k0 + ci * 8);
      short8v vv = *reinterpret_cast<const short8v*>(src);
      int byteoff = (r * 128 + ci * 16) ^ ((r & 7) << 4);
      *reinterpret_cast<short8v*>((char*)(half ? sB : sA) + byteoff) = vv;
    }
    __syncthreads();
#pragma unroll
    for (int ks = 0; ks < 2; ++ks) {
      short8v afr[4], bfr[4];
#pragma unroll
      for (int mt = 0; mt < 4; ++mt) {
        int r = wr * 64 + mt * 16 + lrow;
        afr[mt] = *reinterpret_cast<const short8v*>((char*)sA + ((r * 128 + ks * 64 + lkb2) ^ ((r & 7) << 4)));
      }
#pragma unroll
      for (int nt = 0; nt < 4; ++nt) {
        int r = wc * 64 + nt * 16 + lrow;
        bfr[nt] = *reinterpret_cast<const short8v*>((char*)sB + ((r * 128 + ks * 64 + lkb2) ^ ((r & 7) << 4)));
      }
#pragma unroll
      for (int mt = 0; mt < 4; ++mt)
#pragma unroll
        for (int nt = 0; nt < 4; ++nt)
          acc[mt][nt] = __builtin_amdgcn_mfma_f32_16x16x32_bf16(afr[mt], bfr[nt], acc[mt][nt], 0, 0, 0);
    }
    __syncthreads();
  }
#pragma unroll
  for (int mt = 0; mt < 4; ++mt) {
#pragma unroll
    for (int r = 0; r < 4; ++r) {
      int o = o0 + wr * 64 + mt * 16 + lr4 + r;
      float s3 = fold3[o], b3 = fold3[512 + o];
      float* op = out + ((size_t)b * 512 + o) * NP + n0 + wc * 64 + lrow;
#pragma unroll
      for (int nt = 0; nt < 4; ++nt) {
        float z = acc[mt][nt][r] * s3 + b3;
        op[nt * 16] = leakyf(z, 0.2f);
      }
    }
  }
}

// ---------------------------------------------------------------- launch
extern "C" void kernel_launch(void* const* d_in, const int* in_sizes, int n_in,
                              void* d_out, int out_size, void* d_ws, size_t ws_size,
                              hipStream_t stream) {
  const float* x     = (const float*)d_in[0];
  const float* law1  = (const float*)d_in[1];
  const float* lab1  = (const float*)d_in[2];
  const float* law2  = (const float*)d_in[3];
  const float* lab2  = (const float*)d_in[4];
  const float* law3  = (const float*)d_in[5];
  const float* lab3  = (const float*)d_in[6];
  const float* mlp_w = (const float*)d_in[7];
  const float* mlp_b = (const float*)d_in[8];
  const float* mlp_g = (const float*)d_in[9];
  const float* mlp_be= (const float*)d_in[10];
  const float* mlp_m = (const float*)d_in[11];
  const float* mlp_v = (const float*)d_in[12];
  const float* c1_w  = (const float*)d_in[13];
  const float* bn1_g = (const float*)d_in[14];
  const float* bn1_b = (const float*)d_in[15];
  const float* bn1_m = (const float*)d_in[16];
  const float* bn1_v = (const float*)d_in[17];
  const float* p1_g  = (const float*)d_in[18];
  const float* p1_b  = (const float*)d_in[19];
  const float* p1_m  = (const float*)d_in[20];
  const float* p1_v  = (const float*)d_in[21];
  const float* p1_w  = (const float*)d_in[22];
  const float* p1_wb = (const float*)d_in[23];
  const float* c2_w  = (const float*)d_in[24];
  const float* bn2_g = (const float*)d_in[25];
  const float* bn2_b = (const float*)d_in[26];
  const float* bn2_m = (const float*)d_in[27];
  const float* bn2_v = (const float*)d_in[28];
  const float* p2_g  = (const float*)d_in[29];
  const float* p2_b  = (const float*)d_in[30];
  const float* p2_m  = (const float*)d_in[31];
  const float* p2_v  = (const float*)d_in[32];
  const float* p2_w  = (const float*)d_in[33];
  const float* p2_wb = (const float*)d_in[34];
  const float* c3_w  = (const float*)d_in[35];
  const float* bn3_g = (const float*)d_in[36];
  const float* bn3_b = (const float*)d_in[37];
  const float* bn3_m = (const float*)d_in[38];
  const float* bn3_v = (const float*)d_in[39];

  char* wsb = (char*)d_ws;
  size_t off = 0;
  auto alloc = [&](size_t elems) -> float* {
    float* p = (float*)(wsb + off);
    off += elems * sizeof(float);
    off = (off + 255) & ~(size_t)255;
    return p;
  };
  float* wn1t   = alloc(19 * 64);
  float* wc1t   = alloc(19 * 64);
  float* mlp_wt = alloc(19 * 256);
  float* p1_wt  = alloc(64 * 64);
  unsigned short* Wnc = (unsigned short*)alloc(256 * 192 / 2);
  unsigned short* p2wB = (unsigned short*)alloc(256 * 256 / 2);
  unsigned short* pw1 = (unsigned short*)alloc(8 * 12 * 64 * 8 / 2);
  unsigned short* pw2 = (unsigned short*)alloc(8 * 16 * 64 * 8 / 2);
  unsigned short* W3p  = (unsigned short*)alloc((size_t)512 * 512 / 2);
  float* fold2  = alloc(1024);
  float* fold3  = alloc(1024);
  float* xxbuf  = alloc((size_t)NB * NP);
  float* x_manet= alloc((size_t)NB * 19 * NP);
  float* xmanT  = alloc((size_t)NB * NP * 20);
  float* x_c1   = alloc((size_t)NB * 83 * NP);
  float* hctr1T = alloc((size_t)NB * 64 * NP);
  unsigned short* xc1T = (unsigned short*)alloc((size_t)NB * NP * 96 / 2);
  unsigned short* actT = (unsigned short*)alloc((size_t)NB * NP * 512 / 2);
  int*   idxbuf = (int*)alloc((size_t)NB * NP * KNN);
  float* Dbuf   = (float*)(wsb + off);
  size_t fullD = (size_t)NB * NP * NP * sizeof(float);
  int nbc = (off + fullD <= ws_size) ? NB : 1;

  // merged weight/bn prep (2 launches total)
  prepall_k<<<(PREPALL_TOTAL + 255) / 256, 256, 0, stream>>>(
      c1_w, mlp_w, p1_w, c2_w, p2_w, c3_w,
      bn2_g, bn2_b, bn2_m, bn2_v, p2_g, p2_b, p2_m, p2_v,
      bn3_g, bn3_b, bn3_m, bn3_v,
      wn1t, wc1t, mlp_wt, p1_wt, Wnc, p2wB, W3p, fold2, fold3);
  packall_k<<<56, 256, 0, stream>>>(Wnc, p2wB, pw1, pw2);

  auto knn = [&](const float* src, int C) {
    xx_k<<<(NB * NP + 255) / 256, 256, 0, stream>>>(src, C, xxbuf);
    for (int b0 = 0; b0 < NB; b0 += nbc) {
      dist_k<<<dim3(NP / 64, NP / 64, nbc), 256, 0, stream>>>(src, C, xxbuf, Dbuf, b0);
      topk_k<<<nbc * NP, 64, 0, stream>>>(Dbuf, idxbuf, b0 * NP);
    }
  };

  // stage 1: knn on x (C=3), lafe -> x_manet rows 0..18 + point-major xmanT
  knn(x, 3);
  lafe_k<<<(NB * NP) / 64, 64, 0, stream>>>(x, idxbuf, law1, lab1, law2, lab2, law3, lab3,
                                            x_manet, xmanT);

  // mlp branch -> actT cols [0,256)
  mlp_k<<<dim3(NP / 8, 1, NB), 256, 0, stream>>>(x_manet, mlp_wt, mlp_b, mlp_g, mlp_be, mlp_m, mlp_v, actT);

  // stage 2: knn on x_manet (C=19); hctr1T; conv1+pool -> x_c1 rows 19..82
  knn(x_manet, 19);
  hctr1_k<<<dim3(NP / 4, 1, NB), dim3(64, 4), 0, stream>>>(x_manet, wc1t, hctr1T);
  conv1pool_k<<<NB * NP, 64, 0, stream>>>(xmanT, idxbuf, wn1t, hctr1T,
                                          bn1_g, bn1_b, bn1_m, bn1_v,
                                          p1_g, p1_b, p1_m, p1_v,
                                          p1_wt, p1_wb, x_c1);
  copy_ch_k<<<(NB * 19 * NP + 255) / 256, 256, 0, stream>>>(x_manet, 19, x_c1, 83, 0, 19);

  // stage 3: knn on x_c1 (C=83); transpose-cast; fused MFMA conv2+pool -> actT cols [256,512)
  knn(x_c1, 83);
  t2bf_k<<<dim3(NP / 256, NB), 256, 0, stream>>>(x_c1, xc1T);
  conv2mfma_k<<<NB * NP / 2, 256, 0, stream>>>(xc1T, idxbuf, pw1, pw2, fold2, actT);

  // conv3 (bf16 MFMA, K=512) -> out
  conv3mfma_k<<<dim3(512 / 128, NP / 128, NB), 256, 0, stream>>>(actT, W3p, fold3,
                                                                 (float*)d_out);
}